// Round 3
// baseline (22428.578 us; speedup 1.0000x reference)
//
#include <hip/hip_runtime.h>
#include <cstdint>
#include <cstddef>

#define N_NODES 20000
#define N_EDGES 640000
#define N_GRAPH 64

// ---------------- math helpers ----------------
__device__ __forceinline__ float sigmoidf_(float x) {
    return 1.0f / (1.0f + __expf(-x));
}
__device__ __forceinline__ float tanhf_(float x) {
    float xc = fminf(fmaxf(x, -9.0f), 9.0f);
    float e = __expf(2.0f * xc);
    return (e - 1.0f) / (e + 1.0f);
}

// ---------------- CSR build ----------------
__global__ void count_kernel(const int* __restrict__ dst, int* __restrict__ cnt, int e) {
    int i = blockIdx.x * blockDim.x + threadIdx.x;
    if (i < e) atomicAdd(&cnt[dst[i]], 1);
}

__global__ void scan_kernel(const int* __restrict__ cnt, int* __restrict__ rowstart, int n) {
    __shared__ int buf[1024];
    __shared__ int carry_sh;
    int tid = threadIdx.x;
    if (tid == 0) carry_sh = 0;
    __syncthreads();
    for (int base = 0; base < n; base += 1024) {
        int i = base + tid;
        int v = (i < n) ? cnt[i] : 0;
        buf[tid] = v;
        __syncthreads();
        for (int off = 1; off < 1024; off <<= 1) {
            int t = (tid >= off) ? buf[tid - off] : 0;
            __syncthreads();
            buf[tid] += t;
            __syncthreads();
        }
        int carry = carry_sh;
        if (i < n) rowstart[i] = carry + buf[tid] - v;   // exclusive
        __syncthreads();
        if (tid == 1023) carry_sh = carry + buf[1023];
        __syncthreads();
    }
    if (tid == 0) rowstart[n] = carry_sh;
}

__global__ void dinv_kernel(const int* __restrict__ cnt, float* __restrict__ dinv, int n) {
    int i = blockIdx.x * blockDim.x + threadIdx.x;
    if (i < n) dinv[i] = rsqrtf((float)cnt[i] + 1.0f);   // +1 for self loop; deg >= 1
}

__global__ void fill_kernel(const int* __restrict__ src, const int* __restrict__ dst,
                            const int* __restrict__ rowstart, int* __restrict__ cursor,
                            int* __restrict__ csr_src, int e) {
    int i = blockIdx.x * blockDim.x + threadIdx.x;
    if (i < e) {
        int d = dst[i];
        int pos = rowstart[d] + atomicAdd(&cursor[d], 1);
        csr_src[pos] = src[i];
    }
}

// ---------------- tiled f32 GEMM: C[M,F] = A[M,K] * B (+bias)(relu) ----------------
// BT=false: B is [K,F] row-major.  BT=true: B is [F,K] row-major (use B^T).
template <bool BT, bool RELU, bool BIAS>
__global__ void gemm_kernel(const float* __restrict__ A, const float* __restrict__ B,
                            const float* __restrict__ bias, float* __restrict__ C,
                            int M, int K, int F) {
    __shared__ float As[16][65];
    __shared__ float Bs[16][65];
    int bm = blockIdx.x * 64;
    int bn = blockIdx.y * 64;
    int tid = threadIdx.x;                 // 256 threads
    int tm = (tid >> 4) << 2;
    int tn = (tid & 15) << 2;
    float acc[4][4] = {};
    for (int k0 = 0; k0 < K; k0 += 16) {
        {   // A tile: 64 rows x 16 k
            int idx = tid * 4;
            int m = idx >> 4;
            int kk = idx & 15;
            int gm = bm + m;
            float4 v = make_float4(0.f, 0.f, 0.f, 0.f);
            if (gm < M) v = *(const float4*)&A[(size_t)gm * K + k0 + kk];
            As[kk + 0][m] = v.x; As[kk + 1][m] = v.y; As[kk + 2][m] = v.z; As[kk + 3][m] = v.w;
        }
        if (BT) {
            int idx = tid * 4;
            int nn = idx >> 4;
            int kk = idx & 15;
            float4 v = *(const float4*)&B[(size_t)(bn + nn) * K + k0 + kk];
            Bs[kk + 0][nn] = v.x; Bs[kk + 1][nn] = v.y; Bs[kk + 2][nn] = v.z; Bs[kk + 3][nn] = v.w;
        } else {
            int idx = tid * 4;
            int kk = idx >> 6;
            int nn = idx & 63;
            float4 v = *(const float4*)&B[(size_t)(k0 + kk) * F + bn + nn];
            Bs[kk][nn + 0] = v.x; Bs[kk][nn + 1] = v.y; Bs[kk][nn + 2] = v.z; Bs[kk][nn + 3] = v.w;
        }
        __syncthreads();
#pragma unroll
        for (int kk = 0; kk < 16; ++kk) {
            float av[4], bv[4];
#pragma unroll
            for (int i = 0; i < 4; ++i) av[i] = As[kk][tm + i];
#pragma unroll
            for (int j = 0; j < 4; ++j) bv[j] = Bs[kk][tn + j];
#pragma unroll
            for (int i = 0; i < 4; ++i)
#pragma unroll
                for (int j = 0; j < 4; ++j) acc[i][j] += av[i] * bv[j];
        }
        __syncthreads();
    }
#pragma unroll
    for (int i = 0; i < 4; ++i) {
        int gm = bm + tm + i;
        if (gm >= M) continue;
#pragma unroll
        for (int j = 0; j < 4; ++j) {
            float v = acc[i][j];
            if (BIAS) v += bias[bn + tn + j];
            if (RELU) v = fmaxf(v, 0.0f);
            C[(size_t)gm * F + bn + tn + j] = v;
        }
    }
}

// ---------------- GCN aggregation ----------------
__global__ void agg_kernel(const float* __restrict__ H, const int* __restrict__ rowstart,
                           const int* __restrict__ csr_src, const float* __restrict__ dinv,
                           const float* __restrict__ bias, float* __restrict__ OUT, int F) {
    int n = blockIdx.x;
    int f = threadIdx.x;
    float di = dinv[n];
    int s = rowstart[n], e = rowstart[n + 1];
    float acc = di * H[(size_t)n * F + f];   // self loop
    for (int i = s; i < e; ++i) {
        int src = csr_src[i];
        acc += dinv[src] * H[(size_t)src * F + f];
    }
    OUT[(size_t)n * F + f] = fmaxf(bias[f] + di * acc, 0.0f);
}

__global__ void vadd_kernel(const float* __restrict__ a, const float* __restrict__ b,
                            float* __restrict__ o, int n) {
    int i = blockIdx.x * blockDim.x + threadIdx.x;
    if (i < n) o[i] = a[i] + b[i];
}

// ---------------- LSTM: 512 threads, 1 Whh row/thread, weights PINNED in VGPRs ----------------
#define REP32(OP) OP(0) OP(1) OP(2) OP(3) OP(4) OP(5) OP(6) OP(7) \
                  OP(8) OP(9) OP(10) OP(11) OP(12) OP(13) OP(14) OP(15) \
                  OP(16) OP(17) OP(18) OP(19) OP(20) OP(21) OP(22) OP(23) \
                  OP(24) OP(25) OP(26) OP(27) OP(28) OP(29) OP(30) OP(31)

__global__ __launch_bounds__(512, 2)
void lstm_kernel(const float* __restrict__ xg, const float* __restrict__ whh,
                 float* __restrict__ hs, int steps) {
    __shared__ __align__(16) float h_lds[128];
    __shared__ float gates_lds[512];
    int r = threadIdx.x;                       // gate row 0..511 (i:0-127 f:128-255 g:256-383 o:384-511)
    const float4* h4 = (const float4*)h_lds;

    // Whh row r in 32 named float4s, PINNED: the empty asm makes each value
    // opaque (cannot be rematerialized as a re-load), forcing VGPR residency.
#define LOADW(i) float4 w##i = *(const float4*)&whh[(size_t)r * 128 + (i) * 4]; \
    asm volatile("" : "+v"(w##i.x), "+v"(w##i.y), "+v"(w##i.z), "+v"(w##i.w));
    REP32(LOADW)
#undef LOADW

    if (r < 128) h_lds[r] = 0.0f;
    float c = 0.0f;
    bool is_tanh_gate = (r >= 256) && (r < 384);
    float xnext = xg[r];                       // prefetch step 0
    __syncthreads();

    for (int n = 0; n < steps; ++n) {
        float xcur = xnext;
        if (n + 1 < steps) xnext = xg[(size_t)(n + 1) * 512 + r];   // hide HBM under matvec

        float ax = 0.f, ay = 0.f, az = 0.f, aw = 0.f;   // 4 independent FMA chains
#define DOT(i) { float4 hv = h4[i]; ax += w##i.x * hv.x; ay += w##i.y * hv.y; \
                 az += w##i.z * hv.z; aw += w##i.w * hv.w; }
        REP32(DOT)
#undef DOT
        float g = xcur + (ax + ay) + (az + aw);

        // per-gate activation in parallel across all 512 threads (wave-uniform branch)
        gates_lds[r] = is_tanh_gate ? tanhf_(g) : sigmoidf_(g);
        __syncthreads();

        if (r < 128) {
            float iv = gates_lds[r];
            float fv = gates_lds[r + 128];
            float gv = gates_lds[r + 256];
            float ov = gates_lds[r + 384];
            c = fv * c + iv * gv;
            float hn = ov * tanhf_(c);
            h_lds[r] = hn;
            hs[(size_t)n * 128 + r] = hn;
        }
        __syncthreads();
    }
}

// ---------------- segment sum of hs over sorted batch ----------------
__global__ void pool_kernel(const float* __restrict__ hs, const int* __restrict__ batch,
                            float* __restrict__ poolsum, float* __restrict__ poolcnt, int n) {
    int g = blockIdx.x;
    int f = threadIdx.x;   // 128
    int lo = 0, hi = n;
    while (lo < hi) { int mid = (lo + hi) >> 1; if (batch[mid] < g) lo = mid + 1; else hi = mid; }
    int start = lo;
    lo = 0; hi = n;
    while (lo < hi) { int mid = (lo + hi) >> 1; if (batch[mid] <= g) lo = mid + 1; else hi = mid; }
    int end = lo;
    float acc = 0.0f;
    for (int i = start; i < end; ++i) acc += hs[(size_t)i * 128 + f];
    poolsum[g * 128 + f] = acc;
    if (f == 0) poolcnt[g] = (float)(end - start);
}

// ---------------- head ----------------
__global__ void head_kernel(const float* __restrict__ poolsum, const float* __restrict__ poolcnt,
                            const float* __restrict__ attn_in_w, const float* __restrict__ attn_in_b,
                            const float* __restrict__ attn_out_w, const float* __restrict__ attn_out_b,
                            const float* __restrict__ l1w, const float* __restrict__ l1b,
                            const float* __restrict__ l2w, const float* __restrict__ l2b,
                            float* __restrict__ out) {
    __shared__ float hbar[128], tv[128], pl[128], z1[64], lg[2];
    int g = blockIdx.x, t = threadIdx.x;   // 128 threads
    float cntv = fmaxf(poolcnt[g], 1.0f);
    hbar[t] = poolsum[g * 128 + t] / cntv;
    __syncthreads();
    // v = Wv * hbar + bv  (rows 256..383 of attn_in_w)
    float a = attn_in_b[256 + t];
    for (int k = 0; k < 128; ++k) a += attn_in_w[(256 + t) * 128 + k] * hbar[k];
    tv[t] = a;
    __syncthreads();
    float pv = attn_out_b[t];
    for (int k = 0; k < 128; ++k) pv += attn_out_w[t * 128 + k] * tv[k];
    pl[t] = pv;
    __syncthreads();
    if (t < 64) {
        float z = l1b[t];
        for (int k = 0; k < 128; ++k) z += l1w[t * 128 + k] * pl[k];
        z1[t] = fmaxf(z, 0.0f);
    }
    __syncthreads();
    if (t < 2) {
        float l = l2b[t];
        for (int k = 0; k < 64; ++k) l += l2w[t * 64 + k] * z1[k];
        lg[t] = l;
    }
    __syncthreads();
    if (t == 0) {
        float m = fmaxf(lg[0], lg[1]);
        float ls = m + logf(__expf(lg[0] - m) + __expf(lg[1] - m));
        out[g * 2 + 0] = lg[0] - ls;
        out[g * 2 + 1] = lg[1] - ls;
    }
}

// ---------------- launch ----------------
extern "C" void kernel_launch(void* const* d_in, const int* in_sizes, int n_in,
                              void* d_out, int out_size, void* d_ws, size_t ws_size,
                              hipStream_t stream) {
    const float* x          = (const float*)d_in[0];
    const int*   ei         = (const int*)d_in[1];
    const int*   batch      = (const int*)d_in[2];
    const float* w1 = (const float*)d_in[3];  const float* b1 = (const float*)d_in[4];
    const float* w2 = (const float*)d_in[5];  const float* b2 = (const float*)d_in[6];
    const float* w3 = (const float*)d_in[7];  const float* b3 = (const float*)d_in[8];
    const float* w4 = (const float*)d_in[9];  const float* b4 = (const float*)d_in[10];
    const float* wih = (const float*)d_in[11]; const float* whh = (const float*)d_in[12];
    const float* bih = (const float*)d_in[13]; const float* bhh = (const float*)d_in[14];
    const float* attn_in_w  = (const float*)d_in[15]; const float* attn_in_b  = (const float*)d_in[16];
    const float* attn_out_w = (const float*)d_in[17]; const float* attn_out_b = (const float*)d_in[18];
    const float* l1w = (const float*)d_in[19]; const float* l1b = (const float*)d_in[20];
    const float* l2w = (const float*)d_in[21]; const float* l2b = (const float*)d_in[22];
    float* out = (float*)d_out;

    char* p = (char*)d_ws;
    auto alloc = [&](size_t bytes) {
        char* r = p;
        p += (bytes + 255) & ~(size_t)255;
        return r;
    };
    int*   cnt      = (int*)alloc((size_t)N_NODES * 4);
    int*   cursor   = (int*)alloc((size_t)N_NODES * 4);
    int*   rowstart = (int*)alloc((size_t)(N_NODES + 1) * 4);
    float* dinv     = (float*)alloc((size_t)N_NODES * 4);
    int*   csr      = (int*)alloc((size_t)N_EDGES * 4);
    float* bsum     = (float*)alloc(512 * 4);
    float* poolsum  = (float*)alloc((size_t)N_GRAPH * 128 * 4);
    float* poolcnt  = (float*)alloc((size_t)N_GRAPH * 4);
    float* bufA     = (float*)alloc((size_t)N_NODES * 256 * 4);
    float* bufB     = (float*)alloc((size_t)N_NODES * 256 * 4);
    float* xg       = (float*)alloc((size_t)N_NODES * 512 * 4);
    float* hs       = (float*)alloc((size_t)N_NODES * 128 * 4);

    hipMemsetAsync(cnt, 0, (size_t)N_NODES * 4, stream);
    hipMemsetAsync(cursor, 0, (size_t)N_NODES * 4, stream);

    const int* srcp = ei;
    const int* dstp = ei + N_EDGES;

    int eb = (N_EDGES + 255) / 256;
    int nb = (N_NODES + 255) / 256;
    count_kernel<<<eb, 256, 0, stream>>>(dstp, cnt, N_EDGES);
    scan_kernel<<<1, 1024, 0, stream>>>(cnt, rowstart, N_NODES);
    dinv_kernel<<<nb, 256, 0, stream>>>(cnt, dinv, N_NODES);
    fill_kernel<<<eb, 256, 0, stream>>>(srcp, dstp, rowstart, cursor, csr, N_EDGES);

    int mg = (N_NODES + 63) / 64;   // 313
    // layer 1: H = x @ w1 (K=128,F=64)
    gemm_kernel<false, false, false><<<dim3(mg, 1), 256, 0, stream>>>(x, w1, nullptr, bufA, N_NODES, 128, 64);
    agg_kernel<<<N_NODES, 64, 0, stream>>>(bufA, rowstart, csr, dinv, b1, bufB, 64);
    // layer 2 (K=64,F=64)
    gemm_kernel<false, false, false><<<dim3(mg, 1), 256, 0, stream>>>(bufB, w2, nullptr, bufA, N_NODES, 64, 64);
    agg_kernel<<<N_NODES, 64, 0, stream>>>(bufA, rowstart, csr, dinv, b2, bufB, 64);
    // layer 3 (K=64,F=128)
    gemm_kernel<false, false, false><<<dim3(mg, 2), 256, 0, stream>>>(bufB, w3, nullptr, bufA, N_NODES, 64, 128);
    agg_kernel<<<N_NODES, 128, 0, stream>>>(bufA, rowstart, csr, dinv, b3, bufB, 128);
    // layer 4 (K=128,F=256)
    gemm_kernel<false, false, false><<<dim3(mg, 4), 256, 0, stream>>>(bufB, w4, nullptr, bufA, N_NODES, 128, 256);
    agg_kernel<<<N_NODES, 256, 0, stream>>>(bufA, rowstart, csr, dinv, b4, bufB, 256);

    // xg = h4 @ wih^T + (bih + bhh)   (K=256, F=512, B transposed)
    vadd_kernel<<<2, 256, 0, stream>>>(bih, bhh, bsum, 512);
    gemm_kernel<true, false, true><<<dim3(mg, 8), 256, 0, stream>>>(bufB, wih, bsum, xg, N_NODES, 256, 512);

    // sequential LSTM (1 block, 512 threads, weights pinned in registers)
    lstm_kernel<<<1, 512, 0, stream>>>(xg, whh, hs, N_NODES);

    // pooling + head
    pool_kernel<<<N_GRAPH, 128, 0, stream>>>(hs, batch, poolsum, poolcnt, N_NODES);
    head_kernel<<<N_GRAPH, 128, 0, stream>>>(poolsum, poolcnt, attn_in_w, attn_in_b,
                                             attn_out_w, attn_out_b, l1w, l1b, l2w, l2b, out);
}

// Round 4
// 19398.637 us; speedup vs baseline: 1.1562x; 1.1562x over previous
//
#include <hip/hip_runtime.h>
#include <cstdint>
#include <cstddef>

#define N_NODES 20000
#define N_EDGES 640000
#define N_GRAPH 64

// ---------------- math helpers ----------------
__device__ __forceinline__ float sigmoidf_(float x) {
    return 1.0f / (1.0f + __expf(-x));
}
__device__ __forceinline__ float tanhf_(float x) {
    float xc = fminf(fmaxf(x, -9.0f), 9.0f);
    float e = __expf(2.0f * xc);
    return (e - 1.0f) / (e + 1.0f);
}

// ---------------- CSR build ----------------
__global__ void count_kernel(const int* __restrict__ dst, int* __restrict__ cnt, int e) {
    int i = blockIdx.x * blockDim.x + threadIdx.x;
    if (i < e) atomicAdd(&cnt[dst[i]], 1);
}

__global__ void scan_kernel(const int* __restrict__ cnt, int* __restrict__ rowstart, int n) {
    __shared__ int buf[1024];
    __shared__ int carry_sh;
    int tid = threadIdx.x;
    if (tid == 0) carry_sh = 0;
    __syncthreads();
    for (int base = 0; base < n; base += 1024) {
        int i = base + tid;
        int v = (i < n) ? cnt[i] : 0;
        buf[tid] = v;
        __syncthreads();
        for (int off = 1; off < 1024; off <<= 1) {
            int t = (tid >= off) ? buf[tid - off] : 0;
            __syncthreads();
            buf[tid] += t;
            __syncthreads();
        }
        int carry = carry_sh;
        if (i < n) rowstart[i] = carry + buf[tid] - v;   // exclusive
        __syncthreads();
        if (tid == 1023) carry_sh = carry + buf[1023];
        __syncthreads();
    }
    if (tid == 0) rowstart[n] = carry_sh;
}

__global__ void dinv_kernel(const int* __restrict__ cnt, float* __restrict__ dinv, int n) {
    int i = blockIdx.x * blockDim.x + threadIdx.x;
    if (i < n) dinv[i] = rsqrtf((float)cnt[i] + 1.0f);   // +1 for self loop; deg >= 1
}

__global__ void fill_kernel(const int* __restrict__ src, const int* __restrict__ dst,
                            const int* __restrict__ rowstart, int* __restrict__ cursor,
                            int* __restrict__ csr_src, int e) {
    int i = blockIdx.x * blockDim.x + threadIdx.x;
    if (i < e) {
        int d = dst[i];
        int pos = rowstart[d] + atomicAdd(&cursor[d], 1);
        csr_src[pos] = src[i];
    }
}

// ---------------- tiled f32 GEMM: C[M,F] = A[M,K] * B (+bias)(relu) ----------------
// BT=false: B is [K,F] row-major.  BT=true: B is [F,K] row-major (use B^T).
template <bool BT, bool RELU, bool BIAS>
__global__ void gemm_kernel(const float* __restrict__ A, const float* __restrict__ B,
                            const float* __restrict__ bias, float* __restrict__ C,
                            int M, int K, int F) {
    __shared__ float As[16][65];
    __shared__ float Bs[16][65];
    int bm = blockIdx.x * 64;
    int bn = blockIdx.y * 64;
    int tid = threadIdx.x;                 // 256 threads
    int tm = (tid >> 4) << 2;
    int tn = (tid & 15) << 2;
    float acc[4][4] = {};
    for (int k0 = 0; k0 < K; k0 += 16) {
        {   // A tile: 64 rows x 16 k
            int idx = tid * 4;
            int m = idx >> 4;
            int kk = idx & 15;
            int gm = bm + m;
            float4 v = make_float4(0.f, 0.f, 0.f, 0.f);
            if (gm < M) v = *(const float4*)&A[(size_t)gm * K + k0 + kk];
            As[kk + 0][m] = v.x; As[kk + 1][m] = v.y; As[kk + 2][m] = v.z; As[kk + 3][m] = v.w;
        }
        if (BT) {
            int idx = tid * 4;
            int nn = idx >> 4;
            int kk = idx & 15;
            float4 v = *(const float4*)&B[(size_t)(bn + nn) * K + k0 + kk];
            Bs[kk + 0][nn] = v.x; Bs[kk + 1][nn] = v.y; Bs[kk + 2][nn] = v.z; Bs[kk + 3][nn] = v.w;
        } else {
            int idx = tid * 4;
            int kk = idx >> 6;
            int nn = idx & 63;
            float4 v = *(const float4*)&B[(size_t)(k0 + kk) * F + bn + nn];
            Bs[kk][nn + 0] = v.x; Bs[kk][nn + 1] = v.y; Bs[kk][nn + 2] = v.z; Bs[kk][nn + 3] = v.w;
        }
        __syncthreads();
#pragma unroll
        for (int kk = 0; kk < 16; ++kk) {
            float av[4], bv[4];
#pragma unroll
            for (int i = 0; i < 4; ++i) av[i] = As[kk][tm + i];
#pragma unroll
            for (int j = 0; j < 4; ++j) bv[j] = Bs[kk][tn + j];
#pragma unroll
            for (int i = 0; i < 4; ++i)
#pragma unroll
                for (int j = 0; j < 4; ++j) acc[i][j] += av[i] * bv[j];
        }
        __syncthreads();
    }
#pragma unroll
    for (int i = 0; i < 4; ++i) {
        int gm = bm + tm + i;
        if (gm >= M) continue;
#pragma unroll
        for (int j = 0; j < 4; ++j) {
            float v = acc[i][j];
            if (BIAS) v += bias[bn + tn + j];
            if (RELU) v = fmaxf(v, 0.0f);
            C[(size_t)gm * F + bn + tn + j] = v;
        }
    }
}

// ---------------- GCN aggregation ----------------
__global__ void agg_kernel(const float* __restrict__ H, const int* __restrict__ rowstart,
                           const int* __restrict__ csr_src, const float* __restrict__ dinv,
                           const float* __restrict__ bias, float* __restrict__ OUT, int F) {
    int n = blockIdx.x;
    int f = threadIdx.x;
    float di = dinv[n];
    int s = rowstart[n], e = rowstart[n + 1];
    float acc = di * H[(size_t)n * F + f];   // self loop
    for (int i = s; i < e; ++i) {
        int src = csr_src[i];
        acc += dinv[src] * H[(size_t)src * F + f];
    }
    OUT[(size_t)n * F + f] = fmaxf(bias[f] + di * acc, 0.0f);
}

__global__ void vadd_kernel(const float* __restrict__ a, const float* __restrict__ b,
                            float* __restrict__ o, int n) {
    int i = blockIdx.x * blockDim.x + threadIdx.x;
    if (i < n) o[i] = a[i] + b[i];
}

// ---------------- LSTM: 512 threads, 1 Whh row/thread, weights PINNED in VGPRs ----------------
// amdgpu_waves_per_eu(2,2): max waves/EU = 2 -> RA budget 256 VGPR/thread AND the
// occupancy-driven remat/spill heuristic has nothing to gain above 2 waves.
#define REP32(OP) OP(0) OP(1) OP(2) OP(3) OP(4) OP(5) OP(6) OP(7) \
                  OP(8) OP(9) OP(10) OP(11) OP(12) OP(13) OP(14) OP(15) \
                  OP(16) OP(17) OP(18) OP(19) OP(20) OP(21) OP(22) OP(23) \
                  OP(24) OP(25) OP(26) OP(27) OP(28) OP(29) OP(30) OP(31)

__global__ __launch_bounds__(512)
__attribute__((amdgpu_waves_per_eu(2, 2)))
void lstm_kernel(const float* __restrict__ xg, const float* __restrict__ whh,
                 float* __restrict__ hs, int steps) {
    __shared__ __align__(16) float h_lds[128];
    __shared__ float gates_lds[512];
    int r = threadIdx.x;                       // gate row 0..511 (i:0-127 f:128-255 g:256-383 o:384-511)
    const float4* h4 = (const float4*)h_lds;

    // Whh row r in 32 named float4s, PINNED: the empty asm makes each value
    // opaque (cannot be rematerialized as a re-load), forcing VGPR residency.
#define LOADW(i) float4 w##i = *(const float4*)&whh[(size_t)r * 128 + (i) * 4]; \
    asm volatile("" : "+v"(w##i.x), "+v"(w##i.y), "+v"(w##i.z), "+v"(w##i.w));
    REP32(LOADW)
#undef LOADW

    if (r < 128) h_lds[r] = 0.0f;
    float c = 0.0f;
    bool is_tanh_gate = (r >= 256) && (r < 384);
    float xnext = xg[r];                       // prefetch step 0
    __syncthreads();

    for (int n = 0; n < steps; ++n) {
        float xcur = xnext;
        if (n + 1 < steps) xnext = xg[(size_t)(n + 1) * 512 + r];   // hide HBM under matvec

        float ax = 0.f, ay = 0.f, az = 0.f, aw = 0.f;   // 4 independent FMA chains
#define DOT(i) { float4 hv = h4[i]; ax += w##i.x * hv.x; ay += w##i.y * hv.y; \
                 az += w##i.z * hv.z; aw += w##i.w * hv.w; }
        REP32(DOT)
#undef DOT
        float g = xcur + (ax + ay) + (az + aw);

        // per-gate activation in parallel across all 512 threads (wave-uniform branch)
        gates_lds[r] = is_tanh_gate ? tanhf_(g) : sigmoidf_(g);
        __syncthreads();

        if (r < 128) {
            float iv = gates_lds[r];
            float fv = gates_lds[r + 128];
            float gv = gates_lds[r + 256];
            float ov = gates_lds[r + 384];
            c = fv * c + iv * gv;
            float hn = ov * tanhf_(c);
            h_lds[r] = hn;
            hs[(size_t)n * 128 + r] = hn;
        }
        __syncthreads();
    }
}

// ---------------- segment sum of hs over sorted batch ----------------
__global__ void pool_kernel(const float* __restrict__ hs, const int* __restrict__ batch,
                            float* __restrict__ poolsum, float* __restrict__ poolcnt, int n) {
    int g = blockIdx.x;
    int f = threadIdx.x;   // 128
    int lo = 0, hi = n;
    while (lo < hi) { int mid = (lo + hi) >> 1; if (batch[mid] < g) lo = mid + 1; else hi = mid; }
    int start = lo;
    lo = 0; hi = n;
    while (lo < hi) { int mid = (lo + hi) >> 1; if (batch[mid] <= g) lo = mid + 1; else hi = mid; }
    int end = lo;
    float acc = 0.0f;
    for (int i = start; i < end; ++i) acc += hs[(size_t)i * 128 + f];
    poolsum[g * 128 + f] = acc;
    if (f == 0) poolcnt[g] = (float)(end - start);
}

// ---------------- head ----------------
__global__ void head_kernel(const float* __restrict__ poolsum, const float* __restrict__ poolcnt,
                            const float* __restrict__ attn_in_w, const float* __restrict__ attn_in_b,
                            const float* __restrict__ attn_out_w, const float* __restrict__ attn_out_b,
                            const float* __restrict__ l1w, const float* __restrict__ l1b,
                            const float* __restrict__ l2w, const float* __restrict__ l2b,
                            float* __restrict__ out) {
    __shared__ float hbar[128], tv[128], pl[128], z1[64], lg[2];
    int g = blockIdx.x, t = threadIdx.x;   // 128 threads
    float cntv = fmaxf(poolcnt[g], 1.0f);
    hbar[t] = poolsum[g * 128 + t] / cntv;
    __syncthreads();
    // v = Wv * hbar + bv  (rows 256..383 of attn_in_w)
    float a = attn_in_b[256 + t];
    for (int k = 0; k < 128; ++k) a += attn_in_w[(256 + t) * 128 + k] * hbar[k];
    tv[t] = a;
    __syncthreads();
    float pv = attn_out_b[t];
    for (int k = 0; k < 128; ++k) pv += attn_out_w[t * 128 + k] * tv[k];
    pl[t] = pv;
    __syncthreads();
    if (t < 64) {
        float z = l1b[t];
        for (int k = 0; k < 128; ++k) z += l1w[t * 128 + k] * pl[k];
        z1[t] = fmaxf(z, 0.0f);
    }
    __syncthreads();
    if (t < 2) {
        float l = l2b[t];
        for (int k = 0; k < 64; ++k) l += l2w[t * 64 + k] * z1[k];
        lg[t] = l;
    }
    __syncthreads();
    if (t == 0) {
        float m = fmaxf(lg[0], lg[1]);
        float ls = m + logf(__expf(lg[0] - m) + __expf(lg[1] - m));
        out[g * 2 + 0] = lg[0] - ls;
        out[g * 2 + 1] = lg[1] - ls;
    }
}

// ---------------- launch ----------------
extern "C" void kernel_launch(void* const* d_in, const int* in_sizes, int n_in,
                              void* d_out, int out_size, void* d_ws, size_t ws_size,
                              hipStream_t stream) {
    const float* x          = (const float*)d_in[0];
    const int*   ei         = (const int*)d_in[1];
    const int*   batch      = (const int*)d_in[2];
    const float* w1 = (const float*)d_in[3];  const float* b1 = (const float*)d_in[4];
    const float* w2 = (const float*)d_in[5];  const float* b2 = (const float*)d_in[6];
    const float* w3 = (const float*)d_in[7];  const float* b3 = (const float*)d_in[8];
    const float* w4 = (const float*)d_in[9];  const float* b4 = (const float*)d_in[10];
    const float* wih = (const float*)d_in[11]; const float* whh = (const float*)d_in[12];
    const float* bih = (const float*)d_in[13]; const float* bhh = (const float*)d_in[14];
    const float* attn_in_w  = (const float*)d_in[15]; const float* attn_in_b  = (const float*)d_in[16];
    const float* attn_out_w = (const float*)d_in[17]; const float* attn_out_b = (const float*)d_in[18];
    const float* l1w = (const float*)d_in[19]; const float* l1b = (const float*)d_in[20];
    const float* l2w = (const float*)d_in[21]; const float* l2b = (const float*)d_in[22];
    float* out = (float*)d_out;

    char* p = (char*)d_ws;
    auto alloc = [&](size_t bytes) {
        char* r = p;
        p += (bytes + 255) & ~(size_t)255;
        return r;
    };
    int*   cnt      = (int*)alloc((size_t)N_NODES * 4);
    int*   cursor   = (int*)alloc((size_t)N_NODES * 4);
    int*   rowstart = (int*)alloc((size_t)(N_NODES + 1) * 4);
    float* dinv     = (float*)alloc((size_t)N_NODES * 4);
    int*   csr      = (int*)alloc((size_t)N_EDGES * 4);
    float* bsum     = (float*)alloc(512 * 4);
    float* poolsum  = (float*)alloc((size_t)N_GRAPH * 128 * 4);
    float* poolcnt  = (float*)alloc((size_t)N_GRAPH * 4);
    float* bufA     = (float*)alloc((size_t)N_NODES * 256 * 4);
    float* bufB     = (float*)alloc((size_t)N_NODES * 256 * 4);
    float* xg       = (float*)alloc((size_t)N_NODES * 512 * 4);
    float* hs       = (float*)alloc((size_t)N_NODES * 128 * 4);

    hipMemsetAsync(cnt, 0, (size_t)N_NODES * 4, stream);
    hipMemsetAsync(cursor, 0, (size_t)N_NODES * 4, stream);

    const int* srcp = ei;
    const int* dstp = ei + N_EDGES;

    int eb = (N_EDGES + 255) / 256;
    int nb = (N_NODES + 255) / 256;
    count_kernel<<<eb, 256, 0, stream>>>(dstp, cnt, N_EDGES);
    scan_kernel<<<1, 1024, 0, stream>>>(cnt, rowstart, N_NODES);
    dinv_kernel<<<nb, 256, 0, stream>>>(cnt, dinv, N_NODES);
    fill_kernel<<<eb, 256, 0, stream>>>(srcp, dstp, rowstart, cursor, csr, N_EDGES);

    int mg = (N_NODES + 63) / 64;   // 313
    // layer 1: H = x @ w1 (K=128,F=64)
    gemm_kernel<false, false, false><<<dim3(mg, 1), 256, 0, stream>>>(x, w1, nullptr, bufA, N_NODES, 128, 64);
    agg_kernel<<<N_NODES, 64, 0, stream>>>(bufA, rowstart, csr, dinv, b1, bufB, 64);
    // layer 2 (K=64,F=64)
    gemm_kernel<false, false, false><<<dim3(mg, 1), 256, 0, stream>>>(bufB, w2, nullptr, bufA, N_NODES, 64, 64);
    agg_kernel<<<N_NODES, 64, 0, stream>>>(bufA, rowstart, csr, dinv, b2, bufB, 64);
    // layer 3 (K=64,F=128)
    gemm_kernel<false, false, false><<<dim3(mg, 2), 256, 0, stream>>>(bufB, w3, nullptr, bufA, N_NODES, 64, 128);
    agg_kernel<<<N_NODES, 128, 0, stream>>>(bufA, rowstart, csr, dinv, b3, bufB, 128);
    // layer 4 (K=128,F=256)
    gemm_kernel<false, false, false><<<dim3(mg, 4), 256, 0, stream>>>(bufB, w4, nullptr, bufA, N_NODES, 128, 256);
    agg_kernel<<<N_NODES, 256, 0, stream>>>(bufA, rowstart, csr, dinv, b4, bufB, 256);

    // xg = h4 @ wih^T + (bih + bhh)   (K=256, F=512, B transposed)
    vadd_kernel<<<2, 256, 0, stream>>>(bih, bhh, bsum, 512);
    gemm_kernel<true, false, true><<<dim3(mg, 8), 256, 0, stream>>>(bufB, wih, bsum, xg, N_NODES, 256, 512);

    // sequential LSTM (1 block, 512 threads, weights pinned in registers)
    lstm_kernel<<<1, 512, 0, stream>>>(xg, whh, hs, N_NODES);

    // pooling + head
    pool_kernel<<<N_GRAPH, 128, 0, stream>>>(hs, batch, poolsum, poolcnt, N_NODES);
    head_kernel<<<N_GRAPH, 128, 0, stream>>>(poolsum, poolcnt, attn_in_w, attn_in_b,
                                             attn_out_w, attn_out_b, l1w, l1b, l2w, l2b, out);
}

// Round 5
// 15904.961 us; speedup vs baseline: 1.4102x; 1.2197x over previous
//
#include <hip/hip_runtime.h>
#include <cstdint>
#include <cstddef>

#define N_NODES 20000
#define N_EDGES 640000
#define N_GRAPH 64

typedef __attribute__((ext_vector_type(8))) short bf16x8;
typedef __attribute__((ext_vector_type(4))) float f32x4;

// ---------------- math helpers ----------------
__device__ __forceinline__ float sigmoidf_(float x) {
    return 1.0f / (1.0f + __expf(-x));
}
__device__ __forceinline__ float tanhf_(float x) {
    float xc = fminf(fmaxf(x, -9.0f), 9.0f);
    float e = __expf(2.0f * xc);
    return (e - 1.0f) / (e + 1.0f);
}
__device__ __forceinline__ unsigned short f2bf_(float x) {
    unsigned int u = __builtin_bit_cast(unsigned int, x);
    return (unsigned short)((u + 0x7fffu + ((u >> 16) & 1u)) >> 16);
}

// ---------------- CSR build ----------------
__global__ void count_kernel(const int* __restrict__ dst, int* __restrict__ cnt, int e) {
    int i = blockIdx.x * blockDim.x + threadIdx.x;
    if (i < e) atomicAdd(&cnt[dst[i]], 1);
}

__global__ void scan_kernel(const int* __restrict__ cnt, int* __restrict__ rowstart, int n) {
    __shared__ int buf[1024];
    __shared__ int carry_sh;
    int tid = threadIdx.x;
    if (tid == 0) carry_sh = 0;
    __syncthreads();
    for (int base = 0; base < n; base += 1024) {
        int i = base + tid;
        int v = (i < n) ? cnt[i] : 0;
        buf[tid] = v;
        __syncthreads();
        for (int off = 1; off < 1024; off <<= 1) {
            int t = (tid >= off) ? buf[tid - off] : 0;
            __syncthreads();
            buf[tid] += t;
            __syncthreads();
        }
        int carry = carry_sh;
        if (i < n) rowstart[i] = carry + buf[tid] - v;   // exclusive
        __syncthreads();
        if (tid == 1023) carry_sh = carry + buf[1023];
        __syncthreads();
    }
    if (tid == 0) rowstart[n] = carry_sh;
}

__global__ void dinv_kernel(const int* __restrict__ cnt, float* __restrict__ dinv, int n) {
    int i = blockIdx.x * blockDim.x + threadIdx.x;
    if (i < n) dinv[i] = rsqrtf((float)cnt[i] + 1.0f);   // +1 for self loop; deg >= 1
}

__global__ void fill_kernel(const int* __restrict__ src, const int* __restrict__ dst,
                            const int* __restrict__ rowstart, int* __restrict__ cursor,
                            int* __restrict__ csr_src, int e) {
    int i = blockIdx.x * blockDim.x + threadIdx.x;
    if (i < e) {
        int d = dst[i];
        int pos = rowstart[d] + atomicAdd(&cursor[d], 1);
        csr_src[pos] = src[i];
    }
}

// ---------------- tiled f32 GEMM: C[M,F] = A[M,K] * B (+bias)(relu) ----------------
template <bool BT, bool RELU, bool BIAS>
__global__ void gemm_kernel(const float* __restrict__ A, const float* __restrict__ B,
                            const float* __restrict__ bias, float* __restrict__ C,
                            int M, int K, int F) {
    __shared__ float As[16][65];
    __shared__ float Bs[16][65];
    int bm = blockIdx.x * 64;
    int bn = blockIdx.y * 64;
    int tid = threadIdx.x;                 // 256 threads
    int tm = (tid >> 4) << 2;
    int tn = (tid & 15) << 2;
    float acc[4][4] = {};
    for (int k0 = 0; k0 < K; k0 += 16) {
        {   // A tile: 64 rows x 16 k
            int idx = tid * 4;
            int m = idx >> 4;
            int kk = idx & 15;
            int gm = bm + m;
            float4 v = make_float4(0.f, 0.f, 0.f, 0.f);
            if (gm < M) v = *(const float4*)&A[(size_t)gm * K + k0 + kk];
            As[kk + 0][m] = v.x; As[kk + 1][m] = v.y; As[kk + 2][m] = v.z; As[kk + 3][m] = v.w;
        }
        if (BT) {
            int idx = tid * 4;
            int nn = idx >> 4;
            int kk = idx & 15;
            float4 v = *(const float4*)&B[(size_t)(bn + nn) * K + k0 + kk];
            Bs[kk + 0][nn] = v.x; Bs[kk + 1][nn] = v.y; Bs[kk + 2][nn] = v.z; Bs[kk + 3][nn] = v.w;
        } else {
            int idx = tid * 4;
            int kk = idx >> 6;
            int nn = idx & 63;
            float4 v = *(const float4*)&B[(size_t)(k0 + kk) * F + bn + nn];
            Bs[kk][nn + 0] = v.x; Bs[kk][nn + 1] = v.y; Bs[kk][nn + 2] = v.z; Bs[kk][nn + 3] = v.w;
        }
        __syncthreads();
#pragma unroll
        for (int kk = 0; kk < 16; ++kk) {
            float av[4], bv[4];
#pragma unroll
            for (int i = 0; i < 4; ++i) av[i] = As[kk][tm + i];
#pragma unroll
            for (int j = 0; j < 4; ++j) bv[j] = Bs[kk][tn + j];
#pragma unroll
            for (int i = 0; i < 4; ++i)
#pragma unroll
                for (int j = 0; j < 4; ++j) acc[i][j] += av[i] * bv[j];
        }
        __syncthreads();
    }
#pragma unroll
    for (int i = 0; i < 4; ++i) {
        int gm = bm + tm + i;
        if (gm >= M) continue;
#pragma unroll
        for (int j = 0; j < 4; ++j) {
            float v = acc[i][j];
            if (BIAS) v += bias[bn + tn + j];
            if (RELU) v = fmaxf(v, 0.0f);
            C[(size_t)gm * F + bn + tn + j] = v;
        }
    }
}

// ---------------- GCN aggregation ----------------
__global__ void agg_kernel(const float* __restrict__ H, const int* __restrict__ rowstart,
                           const int* __restrict__ csr_src, const float* __restrict__ dinv,
                           const float* __restrict__ bias, float* __restrict__ OUT, int F) {
    int n = blockIdx.x;
    int f = threadIdx.x;
    float di = dinv[n];
    int s = rowstart[n], e = rowstart[n + 1];
    float acc = di * H[(size_t)n * F + f];   // self loop
    for (int i = s; i < e; ++i) {
        int src = csr_src[i];
        acc += dinv[src] * H[(size_t)src * F + f];
    }
    OUT[(size_t)n * F + f] = fmaxf(bias[f] + di * acc, 0.0f);
}

__global__ void vadd_kernel(const float* __restrict__ a, const float* __restrict__ b,
                            float* __restrict__ o, int n) {
    int i = blockIdx.x * blockDim.x + threadIdx.x;
    if (i < n) o[i] = a[i] + b[i];
}

// ---------------- Whh -> bf16 fragment-order rearrange ----------------
// For wave w (0..7), frag f = rt*4+kt (0..15), lane l (0..63):
//   element j (0..7) = Whh[rt*128 + 16*w + (l&15)][kt*32 + (l>>4)*8 + j]
// stored flat at out[(w*16+f)*64 + l] (16 bytes = 8 bf16).
__global__ void wprep_kernel(const float* __restrict__ whh, uint4* __restrict__ out) {
    int tau = blockIdx.x * blockDim.x + threadIdx.x;   // 0..8191
    if (tau >= 8192) return;
    int l  = tau & 63;
    int f  = (tau >> 6) & 15;
    int w  = tau >> 10;
    int rt = f >> 2, kt = f & 3;
    int grow = rt * 128 + 16 * w + (l & 15);
    int kb   = kt * 32 + (l >> 4) * 8;
    const float* src = whh + (size_t)grow * 128 + kb;
    unsigned int h[8];
#pragma unroll
    for (int j = 0; j < 8; ++j) h[j] = f2bf_(src[j]);
    uint4 v;
    v.x = h[0] | (h[1] << 16);
    v.y = h[2] | (h[3] << 16);
    v.z = h[4] | (h[5] << 16);
    v.w = h[6] | (h[7] << 16);
    out[tau] = v;
}

// ---------------- LSTM via MFMA: 8 waves, Whh bf16 frags in 64 VGPRs/thread ----------------
// gates[512] = Whh @ h + xg per step; B operand = h broadcast into all 16 cols
// (D cols all equal the matvec; no masking). acc C-in = xg (free add).
#define REP16(OP) OP(0) OP(1) OP(2) OP(3) OP(4) OP(5) OP(6) OP(7) \
                  OP(8) OP(9) OP(10) OP(11) OP(12) OP(13) OP(14) OP(15)

__global__ __launch_bounds__(512)
void lstm_mfma_kernel(const float* __restrict__ xg, const bf16x8* wfr,
                      float* hs, int steps) {
    __shared__ __align__(16) unsigned short h_bf[128];
    __shared__ __align__(16) float gates_s[512];
    __shared__ __align__(16) float acts_s[512];
    const int t = threadIdx.x;
    const int w = t >> 6;        // wave 0..7
    const int l = t & 63;        // lane
    const int lg = l >> 4;       // lane group 0..3
    const int rbase = 16 * w + lg * 4;   // row offset within each 128-row gate block

    // A fragments: 16 x bf16x8 = 64 VGPRs. wfr is NOT __restrict__ and hs is NOT
    // __restrict__ -> may alias -> sinking these loads past the hs stores in the
    // loop is illegal. asm pin blocks rematerialization on top.
#define AF(i) bf16x8 af##i = wfr[(size_t)(w * 16 + (i)) * 64 + l]; \
    asm volatile("" : "+v"(af##i));
    REP16(AF)
#undef AF

    if (t < 128) h_bf[t] = 0;
    float c = 0.0f;
    f32x4 xc0 = *(const f32x4*)(xg + 0   + rbase);
    f32x4 xc1 = *(const f32x4*)(xg + 128 + rbase);
    f32x4 xc2 = *(const f32x4*)(xg + 256 + rbase);
    f32x4 xc3 = *(const f32x4*)(xg + 384 + rbase);
    __syncthreads();

    for (int n = 0; n < steps; ++n) {
        // B frags: h[k], k = kt*32 + lg*8 + j  (16 lanes/group same addr -> LDS broadcast)
        bf16x8 b0 = *(const bf16x8*)&h_bf[ 0 + lg * 8];
        bf16x8 b1 = *(const bf16x8*)&h_bf[32 + lg * 8];
        bf16x8 b2 = *(const bf16x8*)&h_bf[64 + lg * 8];
        bf16x8 b3 = *(const bf16x8*)&h_bf[96 + lg * 8];

        // prefetch next step's xg under the MFMAs
        const float* xp = xg + (size_t)((n + 1 < steps) ? n + 1 : n) * 512;
        f32x4 xn0 = *(const f32x4*)(xp + 0   + rbase);
        f32x4 xn1 = *(const f32x4*)(xp + 128 + rbase);
        f32x4 xn2 = *(const f32x4*)(xp + 256 + rbase);
        f32x4 xn3 = *(const f32x4*)(xp + 384 + rbase);

        f32x4 a0 = xc0, a1 = xc1, a2 = xc2, a3 = xc3;   // C-in = xg
        a0 = __builtin_amdgcn_mfma_f32_16x16x32_bf16(af0,  b0, a0, 0, 0, 0);
        a1 = __builtin_amdgcn_mfma_f32_16x16x32_bf16(af4,  b0, a1, 0, 0, 0);
        a2 = __builtin_amdgcn_mfma_f32_16x16x32_bf16(af8,  b0, a2, 0, 0, 0);
        a3 = __builtin_amdgcn_mfma_f32_16x16x32_bf16(af12, b0, a3, 0, 0, 0);
        a0 = __builtin_amdgcn_mfma_f32_16x16x32_bf16(af1,  b1, a0, 0, 0, 0);
        a1 = __builtin_amdgcn_mfma_f32_16x16x32_bf16(af5,  b1, a1, 0, 0, 0);
        a2 = __builtin_amdgcn_mfma_f32_16x16x32_bf16(af9,  b1, a2, 0, 0, 0);
        a3 = __builtin_amdgcn_mfma_f32_16x16x32_bf16(af13, b1, a3, 0, 0, 0);
        a0 = __builtin_amdgcn_mfma_f32_16x16x32_bf16(af2,  b2, a0, 0, 0, 0);
        a1 = __builtin_amdgcn_mfma_f32_16x16x32_bf16(af6,  b2, a1, 0, 0, 0);
        a2 = __builtin_amdgcn_mfma_f32_16x16x32_bf16(af10, b2, a2, 0, 0, 0);
        a3 = __builtin_amdgcn_mfma_f32_16x16x32_bf16(af14, b2, a3, 0, 0, 0);
        a0 = __builtin_amdgcn_mfma_f32_16x16x32_bf16(af3,  b3, a0, 0, 0, 0);
        a1 = __builtin_amdgcn_mfma_f32_16x16x32_bf16(af7,  b3, a1, 0, 0, 0);
        a2 = __builtin_amdgcn_mfma_f32_16x16x32_bf16(af11, b3, a2, 0, 0, 0);
        a3 = __builtin_amdgcn_mfma_f32_16x16x32_bf16(af15, b3, a3, 0, 0, 0);

        // D: row = lg*4 + reg (cols replicated) -> col-group-0 lanes publish raw gates
        if ((l & 15) == 0) {
            *(f32x4*)&gates_s[  0 + rbase] = a0;   // i rows
            *(f32x4*)&gates_s[128 + rbase] = a1;   // f rows
            *(f32x4*)&gates_s[256 + rbase] = a2;   // g rows
            *(f32x4*)&gates_s[384 + rbase] = a3;   // o rows
        }
        __syncthreads();

        // one activation per thread (waves 4-5 = tanh rows: wave-uniform branch)
        {
            float gv = gates_s[t];
            acts_s[t] = (t >= 256 && t < 384) ? tanhf_(gv) : sigmoidf_(gv);
        }
        __syncthreads();

        if (t < 128) {
            float iv = acts_s[t];
            float fv = acts_s[t + 128];
            float gg = acts_s[t + 256];
            float ov = acts_s[t + 384];
            c = fv * c + iv * gg;
            float hn = ov * tanhf_(c);
            hs[(size_t)n * 128 + t] = hn;
            h_bf[t] = f2bf_(hn);
        }
        __syncthreads();

        xc0 = xn0; xc1 = xn1; xc2 = xn2; xc3 = xn3;
    }
}

// ---------------- segment sum of hs over sorted batch ----------------
__global__ void pool_kernel(const float* __restrict__ hs, const int* __restrict__ batch,
                            float* __restrict__ poolsum, float* __restrict__ poolcnt, int n) {
    int g = blockIdx.x;
    int f = threadIdx.x;   // 128
    int lo = 0, hi = n;
    while (lo < hi) { int mid = (lo + hi) >> 1; if (batch[mid] < g) lo = mid + 1; else hi = mid; }
    int start = lo;
    lo = 0; hi = n;
    while (lo < hi) { int mid = (lo + hi) >> 1; if (batch[mid] <= g) lo = mid + 1; else hi = mid; }
    int end = lo;
    float acc = 0.0f;
    for (int i = start; i < end; ++i) acc += hs[(size_t)i * 128 + f];
    poolsum[g * 128 + f] = acc;
    if (f == 0) poolcnt[g] = (float)(end - start);
}

// ---------------- head ----------------
__global__ void head_kernel(const float* __restrict__ poolsum, const float* __restrict__ poolcnt,
                            const float* __restrict__ attn_in_w, const float* __restrict__ attn_in_b,
                            const float* __restrict__ attn_out_w, const float* __restrict__ attn_out_b,
                            const float* __restrict__ l1w, const float* __restrict__ l1b,
                            const float* __restrict__ l2w, const float* __restrict__ l2b,
                            float* __restrict__ out) {
    __shared__ float hbar[128], tv[128], pl[128], z1[64], lg[2];
    int g = blockIdx.x, t = threadIdx.x;   // 128 threads
    float cntv = fmaxf(poolcnt[g], 1.0f);
    hbar[t] = poolsum[g * 128 + t] / cntv;
    __syncthreads();
    float a = attn_in_b[256 + t];
    for (int k = 0; k < 128; ++k) a += attn_in_w[(256 + t) * 128 + k] * hbar[k];
    tv[t] = a;
    __syncthreads();
    float pv = attn_out_b[t];
    for (int k = 0; k < 128; ++k) pv += attn_out_w[t * 128 + k] * tv[k];
    pl[t] = pv;
    __syncthreads();
    if (t < 64) {
        float z = l1b[t];
        for (int k = 0; k < 128; ++k) z += l1w[t * 128 + k] * pl[k];
        z1[t] = fmaxf(z, 0.0f);
    }
    __syncthreads();
    if (t < 2) {
        float l = l2b[t];
        for (int k = 0; k < 64; ++k) l += l2w[t * 64 + k] * z1[k];
        lg[t] = l;
    }
    __syncthreads();
    if (t == 0) {
        float m = fmaxf(lg[0], lg[1]);
        float ls = m + logf(__expf(lg[0] - m) + __expf(lg[1] - m));
        out[g * 2 + 0] = lg[0] - ls;
        out[g * 2 + 1] = lg[1] - ls;
    }
}

// ---------------- launch ----------------
extern "C" void kernel_launch(void* const* d_in, const int* in_sizes, int n_in,
                              void* d_out, int out_size, void* d_ws, size_t ws_size,
                              hipStream_t stream) {
    const float* x          = (const float*)d_in[0];
    const int*   ei         = (const int*)d_in[1];
    const int*   batch      = (const int*)d_in[2];
    const float* w1 = (const float*)d_in[3];  const float* b1 = (const float*)d_in[4];
    const float* w2 = (const float*)d_in[5];  const float* b2 = (const float*)d_in[6];
    const float* w3 = (const float*)d_in[7];  const float* b3 = (const float*)d_in[8];
    const float* w4 = (const float*)d_in[9];  const float* b4 = (const float*)d_in[10];
    const float* wih = (const float*)d_in[11]; const float* whh = (const float*)d_in[12];
    const float* bih = (const float*)d_in[13]; const float* bhh = (const float*)d_in[14];
    const float* attn_in_w  = (const float*)d_in[15]; const float* attn_in_b  = (const float*)d_in[16];
    const float* attn_out_w = (const float*)d_in[17]; const float* attn_out_b = (const float*)d_in[18];
    const float* l1w = (const float*)d_in[19]; const float* l1b = (const float*)d_in[20];
    const float* l2w = (const float*)d_in[21]; const float* l2b = (const float*)d_in[22];
    float* out = (float*)d_out;

    char* p = (char*)d_ws;
    auto alloc = [&](size_t bytes) {
        char* r = p;
        p += (bytes + 255) & ~(size_t)255;
        return r;
    };
    int*   cnt      = (int*)alloc((size_t)N_NODES * 4);
    int*   cursor   = (int*)alloc((size_t)N_NODES * 4);
    int*   rowstart = (int*)alloc((size_t)(N_NODES + 1) * 4);
    float* dinv     = (float*)alloc((size_t)N_NODES * 4);
    int*   csr      = (int*)alloc((size_t)N_EDGES * 4);
    float* bsum     = (float*)alloc(512 * 4);
    float* poolsum  = (float*)alloc((size_t)N_GRAPH * 128 * 4);
    float* poolcnt  = (float*)alloc((size_t)N_GRAPH * 4);
    uint4* wfrag    = (uint4*)alloc((size_t)8192 * 16);   // 128 KB bf16 Whh frags
    float* bufA     = (float*)alloc((size_t)N_NODES * 256 * 4);
    float* bufB     = (float*)alloc((size_t)N_NODES * 256 * 4);
    float* xg       = (float*)alloc((size_t)N_NODES * 512 * 4);
    float* hs       = (float*)alloc((size_t)N_NODES * 128 * 4);

    hipMemsetAsync(cnt, 0, (size_t)N_NODES * 4, stream);
    hipMemsetAsync(cursor, 0, (size_t)N_NODES * 4, stream);

    const int* srcp = ei;
    const int* dstp = ei + N_EDGES;

    int eb = (N_EDGES + 255) / 256;
    int nb = (N_NODES + 255) / 256;
    count_kernel<<<eb, 256, 0, stream>>>(dstp, cnt, N_EDGES);
    scan_kernel<<<1, 1024, 0, stream>>>(cnt, rowstart, N_NODES);
    dinv_kernel<<<nb, 256, 0, stream>>>(cnt, dinv, N_NODES);
    fill_kernel<<<eb, 256, 0, stream>>>(srcp, dstp, rowstart, cursor, csr, N_EDGES);
    wprep_kernel<<<32, 256, 0, stream>>>(whh, wfrag);

    int mg = (N_NODES + 63) / 64;   // 313
    gemm_kernel<false, false, false><<<dim3(mg, 1), 256, 0, stream>>>(x, w1, nullptr, bufA, N_NODES, 128, 64);
    agg_kernel<<<N_NODES, 64, 0, stream>>>(bufA, rowstart, csr, dinv, b1, bufB, 64);
    gemm_kernel<false, false, false><<<dim3(mg, 1), 256, 0, stream>>>(bufB, w2, nullptr, bufA, N_NODES, 64, 64);
    agg_kernel<<<N_NODES, 64, 0, stream>>>(bufA, rowstart, csr, dinv, b2, bufB, 64);
    gemm_kernel<false, false, false><<<dim3(mg, 2), 256, 0, stream>>>(bufB, w3, nullptr, bufA, N_NODES, 64, 128);
    agg_kernel<<<N_NODES, 128, 0, stream>>>(bufA, rowstart, csr, dinv, b3, bufB, 128);
    gemm_kernel<false, false, false><<<dim3(mg, 4), 256, 0, stream>>>(bufB, w4, nullptr, bufA, N_NODES, 128, 256);
    agg_kernel<<<N_NODES, 256, 0, stream>>>(bufA, rowstart, csr, dinv, b4, bufB, 256);

    // xg = h4 @ wih^T + (bih + bhh)
    vadd_kernel<<<2, 256, 0, stream>>>(bih, bhh, bsum, 512);
    gemm_kernel<true, false, true><<<dim3(mg, 8), 256, 0, stream>>>(bufB, wih, bsum, xg, N_NODES, 256, 512);

    // sequential LSTM via MFMA (1 block, 512 threads)
    lstm_mfma_kernel<<<1, 512, 0, stream>>>(xg, (const bf16x8*)wfrag, hs, N_NODES);

    // pooling + head
    pool_kernel<<<N_GRAPH, 128, 0, stream>>>(hs, batch, poolsum, poolcnt, N_NODES);
    head_kernel<<<N_GRAPH, 128, 0, stream>>>(poolsum, poolcnt, attn_in_w, attn_in_b,
                                             attn_out_w, attn_out_b, l1w, l1b, l2w, l2b, out);
}

// Round 6
// 15098.984 us; speedup vs baseline: 1.4854x; 1.0534x over previous
//
#include <hip/hip_runtime.h>
#include <cstdint>
#include <cstddef>

#define N_NODES 20000
#define N_EDGES 640000
#define N_GRAPH 64

typedef __attribute__((ext_vector_type(8))) short bf16x8;
typedef __attribute__((ext_vector_type(4))) float f32x4;

// ---------------- math helpers ----------------
__device__ __forceinline__ float sigmoidf_(float x) {
    return 1.0f / (1.0f + __expf(-x));
}
__device__ __forceinline__ float tanhf_(float x) {
    float xc = fminf(fmaxf(x, -9.0f), 9.0f);
    float e = __expf(2.0f * xc);
    return (e - 1.0f) / (e + 1.0f);
}
__device__ __forceinline__ unsigned short f2bf_(float x) {
    unsigned int u = __builtin_bit_cast(unsigned int, x);
    return (unsigned short)((u + 0x7fffu + ((u >> 16) & 1u)) >> 16);
}

// ---------------- CSR build ----------------
__global__ void count_kernel(const int* __restrict__ dst, int* __restrict__ cnt, int e) {
    int i = blockIdx.x * blockDim.x + threadIdx.x;
    if (i < e) atomicAdd(&cnt[dst[i]], 1);
}

__global__ void scan_kernel(const int* __restrict__ cnt, int* __restrict__ rowstart, int n) {
    __shared__ int buf[1024];
    __shared__ int carry_sh;
    int tid = threadIdx.x;
    if (tid == 0) carry_sh = 0;
    __syncthreads();
    for (int base = 0; base < n; base += 1024) {
        int i = base + tid;
        int v = (i < n) ? cnt[i] : 0;
        buf[tid] = v;
        __syncthreads();
        for (int off = 1; off < 1024; off <<= 1) {
            int t = (tid >= off) ? buf[tid - off] : 0;
            __syncthreads();
            buf[tid] += t;
            __syncthreads();
        }
        int carry = carry_sh;
        if (i < n) rowstart[i] = carry + buf[tid] - v;   // exclusive
        __syncthreads();
        if (tid == 1023) carry_sh = carry + buf[1023];
        __syncthreads();
    }
    if (tid == 0) rowstart[n] = carry_sh;
}

__global__ void dinv_kernel(const int* __restrict__ cnt, float* __restrict__ dinv, int n) {
    int i = blockIdx.x * blockDim.x + threadIdx.x;
    if (i < n) dinv[i] = rsqrtf((float)cnt[i] + 1.0f);   // +1 for self loop; deg >= 1
}

__global__ void fill_kernel(const int* __restrict__ src, const int* __restrict__ dst,
                            const int* __restrict__ rowstart, int* __restrict__ cursor,
                            int* __restrict__ csr_src, int e) {
    int i = blockIdx.x * blockDim.x + threadIdx.x;
    if (i < e) {
        int d = dst[i];
        int pos = rowstart[d] + atomicAdd(&cursor[d], 1);
        csr_src[pos] = src[i];
    }
}

// ---------------- tiled f32 GEMM: C[M,F] = A[M,K] * B (+bias)(relu) ----------------
template <bool BT, bool RELU, bool BIAS>
__global__ void gemm_kernel(const float* __restrict__ A, const float* __restrict__ B,
                            const float* __restrict__ bias, float* __restrict__ C,
                            int M, int K, int F) {
    __shared__ float As[16][65];
    __shared__ float Bs[16][65];
    int bm = blockIdx.x * 64;
    int bn = blockIdx.y * 64;
    int tid = threadIdx.x;                 // 256 threads
    int tm = (tid >> 4) << 2;
    int tn = (tid & 15) << 2;
    float acc[4][4] = {};
    for (int k0 = 0; k0 < K; k0 += 16) {
        {   // A tile: 64 rows x 16 k
            int idx = tid * 4;
            int m = idx >> 4;
            int kk = idx & 15;
            int gm = bm + m;
            float4 v = make_float4(0.f, 0.f, 0.f, 0.f);
            if (gm < M) v = *(const float4*)&A[(size_t)gm * K + k0 + kk];
            As[kk + 0][m] = v.x; As[kk + 1][m] = v.y; As[kk + 2][m] = v.z; As[kk + 3][m] = v.w;
        }
        if (BT) {
            int idx = tid * 4;
            int nn = idx >> 4;
            int kk = idx & 15;
            float4 v = *(const float4*)&B[(size_t)(bn + nn) * K + k0 + kk];
            Bs[kk + 0][nn] = v.x; Bs[kk + 1][nn] = v.y; Bs[kk + 2][nn] = v.z; Bs[kk + 3][nn] = v.w;
        } else {
            int idx = tid * 4;
            int kk = idx >> 6;
            int nn = idx & 63;
            float4 v = *(const float4*)&B[(size_t)(k0 + kk) * F + bn + nn];
            Bs[kk][nn + 0] = v.x; Bs[kk][nn + 1] = v.y; Bs[kk][nn + 2] = v.z; Bs[kk][nn + 3] = v.w;
        }
        __syncthreads();
#pragma unroll
        for (int kk = 0; kk < 16; ++kk) {
            float av[4], bv[4];
#pragma unroll
            for (int i = 0; i < 4; ++i) av[i] = As[kk][tm + i];
#pragma unroll
            for (int j = 0; j < 4; ++j) bv[j] = Bs[kk][tn + j];
#pragma unroll
            for (int i = 0; i < 4; ++i)
#pragma unroll
                for (int j = 0; j < 4; ++j) acc[i][j] += av[i] * bv[j];
        }
        __syncthreads();
    }
#pragma unroll
    for (int i = 0; i < 4; ++i) {
        int gm = bm + tm + i;
        if (gm >= M) continue;
#pragma unroll
        for (int j = 0; j < 4; ++j) {
            float v = acc[i][j];
            if (BIAS) v += bias[bn + tn + j];
            if (RELU) v = fmaxf(v, 0.0f);
            C[(size_t)gm * F + bn + tn + j] = v;
        }
    }
}

// ---------------- GCN aggregation ----------------
__global__ void agg_kernel(const float* __restrict__ H, const int* __restrict__ rowstart,
                           const int* __restrict__ csr_src, const float* __restrict__ dinv,
                           const float* __restrict__ bias, float* __restrict__ OUT, int F) {
    int n = blockIdx.x;
    int f = threadIdx.x;
    float di = dinv[n];
    int s = rowstart[n], e = rowstart[n + 1];
    float acc = di * H[(size_t)n * F + f];   // self loop
    for (int i = s; i < e; ++i) {
        int src = csr_src[i];
        acc += dinv[src] * H[(size_t)src * F + f];
    }
    OUT[(size_t)n * F + f] = fmaxf(bias[f] + di * acc, 0.0f);
}

__global__ void vadd_kernel(const float* __restrict__ a, const float* __restrict__ b,
                            float* __restrict__ o, int n) {
    int i = blockIdx.x * blockDim.x + threadIdx.x;
    if (i < n) o[i] = a[i] + b[i];
}

// ---------------- Whh -> bf16 fragment-order rearrange (16-wave layout) ----------------
// wave w (0..15) owns gate rows [32w, 32w+32); frag f = s*4+kc (s=sub-tile 0/1, kc=k-chunk 0..3)
// lane l: element j = Whh[32w + 16s + (l&15)][kc*32 + (l>>4)*8 + j], flat out[(w*8+f)*64 + l].
__global__ void wprep_kernel(const float* __restrict__ whh, uint4* __restrict__ out) {
    int tau = blockIdx.x * blockDim.x + threadIdx.x;   // 0..8191
    if (tau >= 8192) return;
    int l  = tau & 63;
    int f  = (tau >> 6) & 7;
    int w  = tau >> 9;
    int s  = f >> 2, kc = f & 3;
    int grow = 32 * w + 16 * s + (l & 15);
    int kb   = kc * 32 + (l >> 4) * 8;
    const float* src = whh + (size_t)grow * 128 + kb;
    unsigned int h[8];
#pragma unroll
    for (int j = 0; j < 8; ++j) h[j] = f2bf_(src[j]);
    uint4 v;
    v.x = h[0] | (h[1] << 16);
    v.y = h[2] | (h[3] << 16);
    v.z = h[4] | (h[5] << 16);
    v.w = h[6] | (h[7] << 16);
    out[tau] = v;
}

// ---------------- LSTM via MFMA: 16 waves, 8 A-frags (32 VGPR) per thread ----------------
// gates[512] = Whh@h + xg (C-in); B = h broadcast into 16 cols. Pooling fused into tail
// (batch sorted -> running per-graph register accumulator, one flush per graph).
#define REP8(OP) OP(0) OP(1) OP(2) OP(3) OP(4) OP(5) OP(6) OP(7)

__global__ __launch_bounds__(1024)
__attribute__((amdgpu_waves_per_eu(4, 4)))
void lstm_mfma_kernel(const float* __restrict__ xg, const bf16x8* wfr,
                      const int* __restrict__ batch, float* poolsum, int steps) {
    __shared__ __align__(16) unsigned short h_bf[2][128];
    __shared__ __align__(16) float gates_s[512];
    const int t = threadIdx.x;
    const int w = t >> 6;                 // wave 0..15 -> gate rows [32w, 32w+32)
    const int l = t & 63;
    const int lg = l >> 4;
    const int rbase = 32 * w + 4 * lg;    // D rows: rbase+reg (sub 0), rbase+16+reg (sub 1)

    // A fragments: 8 x bf16x8 = 32 VGPRs/thread. wfr and poolsum may alias (neither
    // __restrict__) and the loop stores to poolsum -> re-loading wfr inside the loop
    // is illegal; asm pin additionally blocks rematerialization.
#define AF(i) bf16x8 af##i = wfr[(size_t)(w * 8 + (i)) * 64 + l]; \
    asm volatile("" : "+v"(af##i));
    REP8(AF)
#undef AF

    if (t < 128) h_bf[0][t] = 0;
    float c = 0.0f, pacc = 0.0f;
    int curb = batch[0];
    f32x4 xc0 = *(const f32x4*)(xg + rbase);
    f32x4 xc1 = *(const f32x4*)(xg + rbase + 16);
    __syncthreads();

    int p = 0;
    for (int n = 0; n < steps; ++n) {
        // B frags: h[kc*32 + lg*8 + j] (16 lanes/group same addr -> LDS broadcast)
        bf16x8 b0 = *(const bf16x8*)&h_bf[p][ 0 + lg * 8];
        bf16x8 b1 = *(const bf16x8*)&h_bf[p][32 + lg * 8];
        bf16x8 b2 = *(const bf16x8*)&h_bf[p][64 + lg * 8];
        bf16x8 b3 = *(const bf16x8*)&h_bf[p][96 + lg * 8];

        // prefetch next step's xg under the MFMAs
        const float* xp = xg + (size_t)((n + 1 < steps) ? n + 1 : n) * 512;
        f32x4 xn0 = *(const f32x4*)(xp + rbase);
        f32x4 xn1 = *(const f32x4*)(xp + rbase + 16);

        f32x4 a0 = xc0, a1 = xc1;   // C-in = xg (free add)
        a0 = __builtin_amdgcn_mfma_f32_16x16x32_bf16(af0, b0, a0, 0, 0, 0);
        a1 = __builtin_amdgcn_mfma_f32_16x16x32_bf16(af4, b0, a1, 0, 0, 0);
        a0 = __builtin_amdgcn_mfma_f32_16x16x32_bf16(af1, b1, a0, 0, 0, 0);
        a1 = __builtin_amdgcn_mfma_f32_16x16x32_bf16(af5, b1, a1, 0, 0, 0);
        a0 = __builtin_amdgcn_mfma_f32_16x16x32_bf16(af2, b2, a0, 0, 0, 0);
        a1 = __builtin_amdgcn_mfma_f32_16x16x32_bf16(af6, b2, a1, 0, 0, 0);
        a0 = __builtin_amdgcn_mfma_f32_16x16x32_bf16(af3, b3, a0, 0, 0, 0);
        a1 = __builtin_amdgcn_mfma_f32_16x16x32_bf16(af7, b3, a1, 0, 0, 0);

        // D cols replicated -> col-0 lanes publish raw gates
        if ((l & 15) == 0) {
            *(f32x4*)&gates_s[rbase]      = a0;
            *(f32x4*)&gates_s[rbase + 16] = a1;
        }
        __syncthreads();

        // tail: full activation + c/h update + fused pooling (waves 0-1)
        if (t < 128) {
            float iv = sigmoidf_(gates_s[t]);
            float fv = sigmoidf_(gates_s[t + 128]);
            float gg = tanhf_(gates_s[t + 256]);
            float ov = sigmoidf_(gates_s[t + 384]);
            c = fv * c + iv * gg;
            float hn = ov * tanhf_(c);
            h_bf[p ^ 1][t] = f2bf_(hn);
            int b = batch[n];             // sorted; same addr across tail -> cached
            if (b != curb) { poolsum[curb * 128 + t] = pacc; pacc = 0.0f; curb = b; }
            pacc += hn;
        }
        __syncthreads();

        xc0 = xn0; xc1 = xn1; p ^= 1;
    }
    if (t < 128) poolsum[curb * 128 + t] = pacc;
}

// ---------------- head (computes counts itself via binary search) ----------------
__global__ void head_kernel(const float* __restrict__ poolsum, const int* __restrict__ batch,
                            int nn,
                            const float* __restrict__ attn_in_w, const float* __restrict__ attn_in_b,
                            const float* __restrict__ attn_out_w, const float* __restrict__ attn_out_b,
                            const float* __restrict__ l1w, const float* __restrict__ l1b,
                            const float* __restrict__ l2w, const float* __restrict__ l2b,
                            float* __restrict__ out) {
    __shared__ float hbar[128], tv[128], pl[128], z1[64], lg[2];
    int g = blockIdx.x, t = threadIdx.x;   // 128 threads
    int lo = 0, hi = nn;
    while (lo < hi) { int m = (lo + hi) >> 1; if (batch[m] < g) lo = m + 1; else hi = m; }
    int s0 = lo;
    lo = 0; hi = nn;
    while (lo < hi) { int m = (lo + hi) >> 1; if (batch[m] <= g) lo = m + 1; else hi = m; }
    int e0 = lo;
    float cntv = fmaxf((float)(e0 - s0), 1.0f);
    hbar[t] = poolsum[g * 128 + t] / cntv;
    __syncthreads();
    float a = attn_in_b[256 + t];
    for (int k = 0; k < 128; ++k) a += attn_in_w[(256 + t) * 128 + k] * hbar[k];
    tv[t] = a;
    __syncthreads();
    float pv = attn_out_b[t];
    for (int k = 0; k < 128; ++k) pv += attn_out_w[t * 128 + k] * tv[k];
    pl[t] = pv;
    __syncthreads();
    if (t < 64) {
        float z = l1b[t];
        for (int k = 0; k < 128; ++k) z += l1w[t * 128 + k] * pl[k];
        z1[t] = fmaxf(z, 0.0f);
    }
    __syncthreads();
    if (t < 2) {
        float lv = l2b[t];
        for (int k = 0; k < 64; ++k) lv += l2w[t * 64 + k] * z1[k];
        lg[t] = lv;
    }
    __syncthreads();
    if (t == 0) {
        float m = fmaxf(lg[0], lg[1]);
        float ls = m + logf(__expf(lg[0] - m) + __expf(lg[1] - m));
        out[g * 2 + 0] = lg[0] - ls;
        out[g * 2 + 1] = lg[1] - ls;
    }
}

// ---------------- launch ----------------
extern "C" void kernel_launch(void* const* d_in, const int* in_sizes, int n_in,
                              void* d_out, int out_size, void* d_ws, size_t ws_size,
                              hipStream_t stream) {
    const float* x          = (const float*)d_in[0];
    const int*   ei         = (const int*)d_in[1];
    const int*   batch      = (const int*)d_in[2];
    const float* w1 = (const float*)d_in[3];  const float* b1 = (const float*)d_in[4];
    const float* w2 = (const float*)d_in[5];  const float* b2 = (const float*)d_in[6];
    const float* w3 = (const float*)d_in[7];  const float* b3 = (const float*)d_in[8];
    const float* w4 = (const float*)d_in[9];  const float* b4 = (const float*)d_in[10];
    const float* wih = (const float*)d_in[11]; const float* whh = (const float*)d_in[12];
    const float* bih = (const float*)d_in[13]; const float* bhh = (const float*)d_in[14];
    const float* attn_in_w  = (const float*)d_in[15]; const float* attn_in_b  = (const float*)d_in[16];
    const float* attn_out_w = (const float*)d_in[17]; const float* attn_out_b = (const float*)d_in[18];
    const float* l1w = (const float*)d_in[19]; const float* l1b = (const float*)d_in[20];
    const float* l2w = (const float*)d_in[21]; const float* l2b = (const float*)d_in[22];
    float* out = (float*)d_out;

    char* p = (char*)d_ws;
    auto alloc = [&](size_t bytes) {
        char* r = p;
        p += (bytes + 255) & ~(size_t)255;
        return r;
    };
    int*   cnt      = (int*)alloc((size_t)N_NODES * 4);
    int*   cursor   = (int*)alloc((size_t)N_NODES * 4);
    int*   rowstart = (int*)alloc((size_t)(N_NODES + 1) * 4);
    float* dinv     = (float*)alloc((size_t)N_NODES * 4);
    int*   csr      = (int*)alloc((size_t)N_EDGES * 4);
    float* bsum     = (float*)alloc(512 * 4);
    float* poolsum  = (float*)alloc((size_t)N_GRAPH * 128 * 4);
    uint4* wfrag    = (uint4*)alloc((size_t)8192 * 16);   // 128 KB bf16 Whh frags
    float* bufA     = (float*)alloc((size_t)N_NODES * 256 * 4);
    float* bufB     = (float*)alloc((size_t)N_NODES * 256 * 4);
    float* xg       = (float*)alloc((size_t)N_NODES * 512 * 4);

    hipMemsetAsync(cnt, 0, (size_t)N_NODES * 4, stream);
    hipMemsetAsync(cursor, 0, (size_t)N_NODES * 4, stream);
    hipMemsetAsync(poolsum, 0, (size_t)N_GRAPH * 128 * 4, stream);   // empty-graph safety

    const int* srcp = ei;
    const int* dstp = ei + N_EDGES;

    int eb = (N_EDGES + 255) / 256;
    int nb = (N_NODES + 255) / 256;
    count_kernel<<<eb, 256, 0, stream>>>(dstp, cnt, N_EDGES);
    scan_kernel<<<1, 1024, 0, stream>>>(cnt, rowstart, N_NODES);
    dinv_kernel<<<nb, 256, 0, stream>>>(cnt, dinv, N_NODES);
    fill_kernel<<<eb, 256, 0, stream>>>(srcp, dstp, rowstart, cursor, csr, N_EDGES);
    wprep_kernel<<<32, 256, 0, stream>>>(whh, wfrag);

    int mg = (N_NODES + 63) / 64;   // 313
    gemm_kernel<false, false, false><<<dim3(mg, 1), 256, 0, stream>>>(x, w1, nullptr, bufA, N_NODES, 128, 64);
    agg_kernel<<<N_NODES, 64, 0, stream>>>(bufA, rowstart, csr, dinv, b1, bufB, 64);
    gemm_kernel<false, false, false><<<dim3(mg, 1), 256, 0, stream>>>(bufB, w2, nullptr, bufA, N_NODES, 64, 64);
    agg_kernel<<<N_NODES, 64, 0, stream>>>(bufA, rowstart, csr, dinv, b2, bufB, 64);
    gemm_kernel<false, false, false><<<dim3(mg, 2), 256, 0, stream>>>(bufB, w3, nullptr, bufA, N_NODES, 64, 128);
    agg_kernel<<<N_NODES, 128, 0, stream>>>(bufA, rowstart, csr, dinv, b3, bufB, 128);
    gemm_kernel<false, false, false><<<dim3(mg, 4), 256, 0, stream>>>(bufB, w4, nullptr, bufA, N_NODES, 128, 256);
    agg_kernel<<<N_NODES, 256, 0, stream>>>(bufA, rowstart, csr, dinv, b4, bufB, 256);

    // xg = h4 @ wih^T + (bih + bhh)
    vadd_kernel<<<2, 256, 0, stream>>>(bih, bhh, bsum, 512);
    gemm_kernel<true, false, true><<<dim3(mg, 8), 256, 0, stream>>>(bufB, wih, bsum, xg, N_NODES, 256, 512);

    // sequential LSTM via MFMA (1 block, 1024 threads, pooling fused)
    lstm_mfma_kernel<<<1, 1024, 0, stream>>>(xg, (const bf16x8*)wfrag, batch, poolsum, N_NODES);

    // head
    head_kernel<<<N_GRAPH, 128, 0, stream>>>(poolsum, batch, N_NODES,
                                             attn_in_w, attn_in_b, attn_out_w, attn_out_b,
                                             l1w, l1b, l2w, l2b, out);
}